// Round 6
// baseline (195.983 us; speedup 1.0000x reference)
//
#include <hip/hip_runtime.h>
#include <cmath>

constexpr int NOBJ = 256, CNUM = 151, DDIM = 512;
constexpr int NG1 = 512;  // GEMM blocks in k_G1 (16 mb x 8 jb x 4 z)

__device__ __forceinline__ float sigf(float x) { return 1.0f / (1.0f + __expf(-x)); }
__device__ __forceinline__ float tanhf_(float x) {
  float e = __expf(-2.0f * fabsf(x));
  float y = (1.0f - e) / (1.0f + e);
  return copysignf(y, x);
}
__device__ __forceinline__ float4 ld4(const float* p) { return *reinterpret_cast<const float4*>(p); }
__device__ __forceinline__ void st4(float* p, float4 v) { *reinterpret_cast<float4*>(p) = v; }

// ---------------------------------------------------------------------------
// k_G1: hw_z = H*Wsum_z^T (z=0,1,2 folded on load), hu3 = H*w3u^T + b3u.
// Tile 16m x 64j, wave = 64 j-lanes x 4 m (micro 4x1). grid NG1 (+604 wcs
// blocks on the first launch). A-reads are wave-UNIFORM (HW broadcast ~free
// LDS bytes); B-reads per-lane b128, banks perfectly spread. ~1 B/FMA.
// Epilogue: psum[z][16][512] column partials (deterministic tree).
// Fused tail blocks (bx>=NG1): Wcs[co][d] = sum_c wc[co][c*512+d].
// ---------------------------------------------------------------------------
__global__ void __launch_bounds__(256) k_G1(
    const float* __restrict__ H, const float* __restrict__ w3w,
    const float* __restrict__ w4w, const float* __restrict__ w5w,
    const float* __restrict__ w3u, const float* __restrict__ b3u,
    float* __restrict__ hw, float* __restrict__ psum,
    const float* __restrict__ wc, float* __restrict__ Wcs) {
  __shared__ float smem[1024 + 4096];  // sA [g][16m][4] | sB [g][64j][4]
  const int t = threadIdx.x;
  const int bx = blockIdx.x;
  if (bx >= NG1) {  // ---- fused Wcs reduction (only on the grid-1116 launch) ----
    const int bw = bx - NG1;
    const int co = bw >> 2, q = bw & 3;
    const int d = q * 128 + (t & 31) * 4;
    const int g = t >> 5;
    const float* row = wc + (size_t)co * (CNUM * DDIM);
    float4 s = make_float4(0.f, 0.f, 0.f, 0.f);
    for (int c = g; c < CNUM; c += 8) {
      const float4 v = ld4(row + c * DDIM + d);
      s.x += v.x; s.y += v.y; s.z += v.z; s.w += v.w;
    }
    float4* red = reinterpret_cast<float4*>(smem);
    red[t] = s;
    __syncthreads();
    if (t < 128) { red[t].x += red[t+128].x; red[t].y += red[t+128].y;
                   red[t].z += red[t+128].z; red[t].w += red[t+128].w; }
    __syncthreads();
    if (t < 64)  { red[t].x += red[t+64].x; red[t].y += red[t+64].y;
                   red[t].z += red[t+64].z; red[t].w += red[t+64].w; }
    __syncthreads();
    if (t < 32) {
      float4 o = red[t];
      o.x += red[t+32].x; o.y += red[t+32].y; o.z += red[t+32].z; o.w += red[t+32].w;
      st4(Wcs + co * DDIM + q * 128 + t * 4, o);
    }
    return;
  }
  float* sA = smem;
  float* sB = smem + 1024;
  const int z = bx >> 7;
  const int jb = (bx >> 4) & 7;
  const int mb = bx & 15;
  const int m0 = mb * 16, j0 = jb * 64;
  const float* W = (z == 0) ? w3w : (z == 1) ? w4w : (z == 2) ? w5w : w3u;
  const int lane = t & 63, wv = t >> 6;
  const int ar = t >> 4, ag = t & 15;        // A stage: row ar, k-group ag
  const int bj = t >> 2, bks = (t & 3) * 16; // B stage: row bj, 16 k's
  float4 ra, rb[8];
  float acc[4] = {0.f, 0.f, 0.f, 0.f};

#define G1_LOAD(k0)                                                           \
  {                                                                           \
    ra = ld4(H + (size_t)(m0 + ar) * DDIM + (k0) + ag * 4);                   \
    if (z < 3) {                                                              \
      const float* bp = W + (size_t)(j0 + bj) * 1024 + (k0) + bks;            \
      rb[0] = ld4(bp);       rb[1] = ld4(bp + 4);                             \
      rb[2] = ld4(bp + 8);   rb[3] = ld4(bp + 12);                            \
      rb[4] = ld4(bp + 512); rb[5] = ld4(bp + 516);                           \
      rb[6] = ld4(bp + 520); rb[7] = ld4(bp + 524);                           \
    } else {                                                                  \
      const float* bp = W + (size_t)(j0 + bj) * DDIM + (k0) + bks;            \
      rb[0] = ld4(bp);     rb[1] = ld4(bp + 4);                               \
      rb[2] = ld4(bp + 8); rb[3] = ld4(bp + 12);                              \
    }                                                                         \
  }

  G1_LOAD(0);
  for (int c = 0; c < 8; ++c) {
    __syncthreads();
    st4(sA + ag * 64 + ar * 4, ra);
    const int g0 = bks >> 2;
    if (z < 3) {
#pragma unroll
      for (int i = 0; i < 4; ++i)
        st4(sB + (g0 + i) * 256 + bj * 4,
            make_float4(rb[i].x + rb[4+i].x, rb[i].y + rb[4+i].y,
                        rb[i].z + rb[4+i].z, rb[i].w + rb[4+i].w));
    } else {
#pragma unroll
      for (int i = 0; i < 4; ++i) st4(sB + (g0 + i) * 256 + bj * 4, rb[i]);
    }
    __syncthreads();
    if (c < 7) G1_LOAD((c + 1) * 64);
#pragma unroll
    for (int g = 0; g < 16; ++g) {
      const float4 bv = ld4(sB + g * 256 + lane * 4);  // unique per lane
#pragma unroll
      for (int i = 0; i < 4; ++i) {
        const float4 a = ld4(sA + g * 64 + (wv * 4 + i) * 4);  // wave-uniform
        acc[i] = fmaf(a.x, bv.x, acc[i]);
        acc[i] = fmaf(a.y, bv.y, acc[i]);
        acc[i] = fmaf(a.z, bv.z, acc[i]);
        acc[i] = fmaf(a.w, bv.w, acc[i]);
      }
    }
  }
#undef G1_LOAD
  float* op = hw + (size_t)z * (NOBJ * DDIM);
  const float bias = (z == 3) ? b3u[j0 + lane] : 0.f;
#pragma unroll
  for (int i = 0; i < 4; ++i)
    op[(size_t)(m0 + wv * 4 + i) * DDIM + j0 + lane] = acc[i] + bias;
  if (z < 3) {  // deterministic column partials over this block's 16 rows
    const float s = acc[0] + acc[1] + acc[2] + acc[3];
    __syncthreads();
    sA[wv * 64 + lane] = s;
    __syncthreads();
    if (t < 64)
      psum[z * 8192 + mb * 512 + j0 + t] =
          sA[t] + sA[64 + t] + sA[128 + t] + sA[192 + t];
  }
}

// ---------------------------------------------------------------------------
// k_G2: rv = sig(fac*(svh4-hw4)+b4w+hu3); acc = (rv.H)*w5u^T; fused GRU
// update in epilogue. Tile 4m x 64j (wave = 1m x 64j), grid (64,8)=512.
// svh_z rebuilt from the 16 psum partials in LDS.
// ---------------------------------------------------------------------------
__global__ void __launch_bounds__(256) k_G2(
    const float* __restrict__ Hc, const float* __restrict__ hw,
    const float* __restrict__ psum, const float* __restrict__ mat,
    const float* __restrict__ b3w, const float* __restrict__ b4w,
    const float* __restrict__ b5w, const float* __restrict__ w5u,
    const float* __restrict__ b5u, float* __restrict__ Hn) {
  __shared__ float sA[256];    // [g][4m][4]
  __shared__ float sB[4096];   // [g][64j][4]
  __shared__ float sv4[512];
  __shared__ float sv35[128];
  const int t = threadIdx.x;
  const int m0 = blockIdx.x * 4, j0 = blockIdx.y * 64;
  const int lane = t & 63, wv = t >> 6;
  const float fac = mat[0] * (float)CNUM;
  const float* hw3 = hw;
  const float* hw4 = hw + NOBJ * DDIM;
  const float* hw5 = hw + 2 * NOBJ * DDIM;
  const float* hu3 = hw + 3 * NOBJ * DDIM;
  {  // svh4 (full K)
    float a = 0.f, b = 0.f;
#pragma unroll
    for (int mt = 0; mt < 16; ++mt) {
      a += psum[8192 + mt * 512 + t];
      b += psum[8192 + mt * 512 + 256 + t];
    }
    sv4[t] = a; sv4[256 + t] = b;
  }
  if (t < 64) {  // svh3, svh5 at this j-panel
    const int j = j0 + t;
    float a = 0.f, b = 0.f;
#pragma unroll
    for (int mt = 0; mt < 16; ++mt) {
      a += psum[mt * 512 + j];
      b += psum[2 * 8192 + mt * 512 + j];
    }
    sv35[t] = a; sv35[64 + t] = b;
  }
  const int ak = t & 63, am = t >> 6;
  const int bj = t >> 2, bks = (t & 3) * 16;
  float rh4, ru3, rhh, rb4;
  float4 rb[4];
  float acc = 0.f;

#define G2_LOAD(k0)                                                   \
  {                                                                   \
    const int ia = (m0 + am) * DDIM + (k0) + ak;                      \
    rh4 = hw4[ia]; ru3 = hu3[ia]; rhh = Hc[ia]; rb4 = b4w[(k0) + ak]; \
    const float* bp = w5u + (size_t)(j0 + bj) * DDIM + (k0) + bks;    \
    rb[0] = ld4(bp);     rb[1] = ld4(bp + 4);                         \
    rb[2] = ld4(bp + 8); rb[3] = ld4(bp + 12);                        \
  }

  G2_LOAD(0);
  for (int c = 0; c < 8; ++c) {
    const int k0 = c * 64;
    __syncthreads();
    {
      const float rv = sigf(fac * (sv4[k0 + ak] - rh4) + rb4 + ru3);
      sA[(ak >> 2) * 16 + am * 4 + (ak & 3)] = rv * rhh;
      const int g0 = bks >> 2;
#pragma unroll
      for (int i = 0; i < 4; ++i) st4(sB + (g0 + i) * 256 + bj * 4, rb[i]);
    }
    __syncthreads();
    if (c < 7) G2_LOAD((c + 1) * 64);
#pragma unroll
    for (int g = 0; g < 16; ++g) {
      const float4 a = ld4(sA + g * 16 + wv * 4);       // wave-uniform
      const float4 bv = ld4(sB + g * 256 + lane * 4);   // unique per lane
      acc = fmaf(a.x, bv.x, acc);
      acc = fmaf(a.y, bv.y, acc);
      acc = fmaf(a.z, bv.z, acc);
      acc = fmaf(a.w, bv.w, acc);
    }
  }
#undef G2_LOAD
  const int m = m0 + wv, j = j0 + lane;
  const int idx = m * DDIM + j;
  const float zv = sigf(fac * (sv35[lane] - hw3[idx]) + b3w[j] + hu3[idx]);
  const float hv = tanhf_(fac * (sv35[64 + lane] - hw5[idx]) + b5w[j] + acc + b5u[j]);
  Hn[idx] = (1.f - zv) * Hc[idx] + zv * hv;
}

// ---------------------------------------------------------------------------
// k_out: Po[s] = (s?X:H) * wo[:, s*512:(s+1)*512]^T  (split at the concat).
// Tile 8m x 64j (wave = 2m x 64j), grid (32,8,2) = 512.
// ---------------------------------------------------------------------------
__global__ void __launch_bounds__(256) k_out(const float* __restrict__ H,
                                             const float* __restrict__ X,
                                             const float* __restrict__ wo,
                                             float* __restrict__ Po) {
  __shared__ float sA[512];
  __shared__ float sB[4096];
  const int t = threadIdx.x;
  const int m0 = blockIdx.x * 8, j0 = blockIdx.y * 64;
  const int s = blockIdx.z;
  const float* A = s ? X : H;
  const int lane = t & 63, wv = t >> 6;
  const int ak = t & 63, am = (t >> 6) * 2;
  const int bj = t >> 2, bks = (t & 3) * 16;
  float ra0, ra1;
  float4 rb[4];
  float acc[2] = {0.f, 0.f};

#define KO_LOAD(k0)                                                         \
  {                                                                         \
    ra0 = A[(m0 + am) * DDIM + (k0) + ak];                                  \
    ra1 = A[(m0 + am + 1) * DDIM + (k0) + ak];                              \
    const float* bp = wo + (size_t)(j0 + bj) * 1024 + s * 512 + (k0) + bks; \
    rb[0] = ld4(bp);     rb[1] = ld4(bp + 4);                               \
    rb[2] = ld4(bp + 8); rb[3] = ld4(bp + 12);                              \
  }

  KO_LOAD(0);
  for (int c = 0; c < 8; ++c) {
    __syncthreads();
    sA[(ak >> 2) * 32 + am * 4 + (ak & 3)] = ra0;
    sA[(ak >> 2) * 32 + (am + 1) * 4 + (ak & 3)] = ra1;
    const int g0 = bks >> 2;
#pragma unroll
    for (int i = 0; i < 4; ++i) st4(sB + (g0 + i) * 256 + bj * 4, rb[i]);
    __syncthreads();
    if (c < 7) KO_LOAD((c + 1) * 64);
#pragma unroll
    for (int g = 0; g < 16; ++g) {
      const float4 a0 = ld4(sA + g * 32 + (wv * 2) * 4);
      const float4 a1 = ld4(sA + g * 32 + (wv * 2 + 1) * 4);
      const float4 bv = ld4(sB + g * 256 + lane * 4);
      acc[0] = fmaf(a0.x, bv.x, acc[0]); acc[0] = fmaf(a0.y, bv.y, acc[0]);
      acc[0] = fmaf(a0.z, bv.z, acc[0]); acc[0] = fmaf(a0.w, bv.w, acc[0]);
      acc[1] = fmaf(a1.x, bv.x, acc[1]); acc[1] = fmaf(a1.y, bv.y, acc[1]);
      acc[1] = fmaf(a1.z, bv.z, acc[1]); acc[1] = fmaf(a1.w, bv.w, acc[1]);
    }
  }
#undef KO_LOAD
#pragma unroll
  for (int i = 0; i < 2; ++i)
    Po[(size_t)s * (NOBJ * DDIM) + (size_t)(m0 + wv * 2 + i) * DDIM + j0 + lane] = acc[i];
}

// ---------------------------------------------------------------------------
// k_obj: out = relu(Po0+Po1+bo) * Wcs^T + bc. Tile 8m x 64j, grid (32,3)=96.
// ---------------------------------------------------------------------------
__global__ void __launch_bounds__(256) k_obj(const float* __restrict__ Po,
                                             const float* __restrict__ bo,
                                             const float* __restrict__ Wcs,
                                             const float* __restrict__ bc,
                                             float* __restrict__ out) {
  __shared__ float sA[512];
  __shared__ float sB[4096];
  const int t = threadIdx.x;
  const int m0 = blockIdx.x * 8, j0 = blockIdx.y * 64;
  const int lane = t & 63, wv = t >> 6;
  const int ak = t & 63, am = (t >> 6) * 2;
  const int bj = t >> 2, bks = (t & 3) * 16;
  const int co = j0 + bj;
  float ra0, ra1;
  float4 rb[4];
  float acc[2] = {0.f, 0.f};

#define OB_LOAD(k0)                                                       \
  {                                                                       \
    const int i0 = (m0 + am) * DDIM + (k0) + ak;                          \
    const int i1 = i0 + DDIM;                                             \
    const float bb = bo[(k0) + ak];                                       \
    ra0 = fmaxf(Po[i0] + Po[NOBJ * DDIM + i0] + bb, 0.f);                 \
    ra1 = fmaxf(Po[i1] + Po[NOBJ * DDIM + i1] + bb, 0.f);                 \
    if (co < CNUM) {                                                      \
      const float* bp = Wcs + (size_t)co * DDIM + (k0) + bks;             \
      rb[0] = ld4(bp);     rb[1] = ld4(bp + 4);                           \
      rb[2] = ld4(bp + 8); rb[3] = ld4(bp + 12);                          \
    } else {                                                              \
      rb[0] = rb[1] = rb[2] = rb[3] = make_float4(0.f, 0.f, 0.f, 0.f);    \
    }                                                                     \
  }

  OB_LOAD(0);
  for (int c = 0; c < 8; ++c) {
    __syncthreads();
    sA[(ak >> 2) * 32 + am * 4 + (ak & 3)] = ra0;
    sA[(ak >> 2) * 32 + (am + 1) * 4 + (ak & 3)] = ra1;
    const int g0 = bks >> 2;
#pragma unroll
    for (int i = 0; i < 4; ++i) st4(sB + (g0 + i) * 256 + bj * 4, rb[i]);
    __syncthreads();
    if (c < 7) OB_LOAD((c + 1) * 64);
#pragma unroll
    for (int g = 0; g < 16; ++g) {
      const float4 a0 = ld4(sA + g * 32 + (wv * 2) * 4);
      const float4 a1 = ld4(sA + g * 32 + (wv * 2 + 1) * 4);
      const float4 bv = ld4(sB + g * 256 + lane * 4);
      acc[0] = fmaf(a0.x, bv.x, acc[0]); acc[0] = fmaf(a0.y, bv.y, acc[0]);
      acc[0] = fmaf(a0.z, bv.z, acc[0]); acc[0] = fmaf(a0.w, bv.w, acc[0]);
      acc[1] = fmaf(a1.x, bv.x, acc[1]); acc[1] = fmaf(a1.y, bv.y, acc[1]);
      acc[1] = fmaf(a1.z, bv.z, acc[1]); acc[1] = fmaf(a1.w, bv.w, acc[1]);
    }
  }
#undef OB_LOAD
  const int c_ = j0 + lane;
  if (c_ < CNUM) {
#pragma unroll
    for (int i = 0; i < 2; ++i)
      out[(m0 + wv * 2 + i) * CNUM + c_] = acc[i] + bc[c_];
  }
}

extern "C" void kernel_launch(void* const* d_in, const int* in_sizes, int n_in,
                              void* d_out, int out_size, void* d_ws, size_t ws_size,
                              hipStream_t stream) {
  const float* X = (const float*)d_in[0];
  const float* mat = (const float*)d_in[1];
  const float* w3w = (const float*)d_in[2];
  const float* b3w = (const float*)d_in[3];
  const float* w3u = (const float*)d_in[4];
  const float* b3u = (const float*)d_in[5];
  const float* w4w = (const float*)d_in[6];
  const float* b4w = (const float*)d_in[7];
  // d_in[8], d_in[9] (w4u, b4u) unused — reference reuses w3u/b3u (faithful bug)
  const float* w5w = (const float*)d_in[10];
  const float* b5w = (const float*)d_in[11];
  const float* w5u = (const float*)d_in[12];
  const float* b5u = (const float*)d_in[13];
  const float* wo = (const float*)d_in[14];
  const float* bo = (const float*)d_in[15];
  const float* wc = (const float*)d_in[16];
  const float* bc = (const float*)d_in[17];
  float* out = (float*)d_out;
  float* ws = (float*)d_ws;

  // workspace (floats): ~4.3 MB
  float* Wcs = ws;               // 151*512    = 77312
  float* hw = Wcs + 77312;       // 4*256*512  = 524288 (hw3,hw4,hw5,hu3)
  float* psum = hw + 524288;     // 3*16*512   = 24576
  float* H0 = psum + 24576;      // 131072
  float* H1 = H0 + 131072;       // 131072
  float* Po = H1 + 131072;       // 2*131072

  // iter 1 (Hc = X): G1 with wcs blocks appended (memory-bound, co-scheduled)
  k_G1<<<NG1 + CNUM * 4, 256, 0, stream>>>(X, w3w, w4w, w5w, w3u, b3u, hw, psum, wc, Wcs);
  k_G2<<<dim3(64, 8), 256, 0, stream>>>(X, hw, psum, mat, b3w, b4w, b5w, w5u, b5u, H0);
  // iter 2
  k_G1<<<NG1, 256, 0, stream>>>(H0, w3w, w4w, w5w, w3u, b3u, hw, psum, wc, Wcs);
  k_G2<<<dim3(64, 8), 256, 0, stream>>>(H0, hw, psum, mat, b3w, b4w, b5w, w5u, b5u, H1);
  // iter 3
  k_G1<<<NG1, 256, 0, stream>>>(H1, w3w, w4w, w5w, w3u, b3u, hw, psum, wc, Wcs);
  k_G2<<<dim3(64, 8), 256, 0, stream>>>(H1, hw, psum, mat, b3w, b4w, b5w, w5u, b5u, H0);
  // epilogue
  k_out<<<dim3(32, 8, 2), 256, 0, stream>>>(H0, X, wo, Po);
  k_obj<<<dim3(32, 3), 256, 0, stream>>>(Po, bo, Wcs, bc, out);
}

// Round 7
// 182.491 us; speedup vs baseline: 1.0739x; 1.0739x over previous
//
#include <hip/hip_runtime.h>
#include <cmath>

constexpr int NOBJ = 256, CNUM = 151, DDIM = 512;
constexpr int NG1 = 256;  // G1 GEMM blocks: 4z x 8jb x 8mb (XCD-swizzled)

__device__ __forceinline__ float sigf(float x) { return 1.0f / (1.0f + __expf(-x)); }
__device__ __forceinline__ float tanhf_(float x) {
  float e = __expf(-2.0f * fabsf(x));
  float y = (1.0f - e) / (1.0f + e);
  return copysignf(y, x);
}
__device__ __forceinline__ float4 ld4(const float* p) { return *reinterpret_cast<const float4*>(p); }

// store float4 v into LDS with word stride S (scalar b32 stores, lanes stride-1 => conflict-free)
#define ST4S(dst, S, v) { (dst)[0] = (v).x; (dst)[(S)] = (v).y; (dst)[2*(S)] = (v).z; (dst)[3*(S)] = (v).w; }

// ---------------------------------------------------------------------------
// k_G1: hw_z = H*Wsum_z^T (z=0..2 folded on load), hu3 = H*w3u^T + b3u.
// Tile 32m x 64j, 4 waves x 8m, lane = j. grid NG1 (+604 Wcs tail blocks on
// the first launch). XCD swizzle: xcd=bid&7 owns 4 (z,jb) panels x 8 mb, so
// each weight panel lives in exactly one XCD L2.
// LDS: sA[k][m] (stores stride-1 free, reads wave-uniform b128 broadcast),
//      sB[k][j] (lane-major loads, stride-1 scalar stores free, b32 reads free)
// Epilogue: psum[z][8mb][512] deterministic column partials.
// ---------------------------------------------------------------------------
__global__ void __launch_bounds__(256) k_G1(
    const float* __restrict__ H, const float* __restrict__ w3w,
    const float* __restrict__ w4w, const float* __restrict__ w5w,
    const float* __restrict__ w3u, const float* __restrict__ b3u,
    float* __restrict__ hw, float* __restrict__ psum,
    const float* __restrict__ wc, float* __restrict__ Wcs) {
  __shared__ float sA[64 * 32];  // [k][m]
  __shared__ float sB[64 * 64];  // [k][j]
  const int t = threadIdx.x;
  const int bx = blockIdx.x;
  if (bx >= NG1) {  // ---- fused Wcs tail (first launch only): streams wc ----
    const int bw = bx - NG1;
    const int co = bw >> 2, q = bw & 3;
    const int d = q * 128 + (t & 31) * 4;
    const int g = t >> 5;
    const float* row = wc + (size_t)co * (CNUM * DDIM);
    float4 s = make_float4(0.f, 0.f, 0.f, 0.f);
    for (int c = g; c < CNUM; c += 8) {
      const float4 v = ld4(row + c * DDIM + d);
      s.x += v.x; s.y += v.y; s.z += v.z; s.w += v.w;
    }
    float4* red = reinterpret_cast<float4*>(sA);
    red[t] = s;
    __syncthreads();
    if (t < 128) { red[t].x += red[t+128].x; red[t].y += red[t+128].y;
                   red[t].z += red[t+128].z; red[t].w += red[t+128].w; }
    __syncthreads();
    if (t < 64)  { red[t].x += red[t+64].x; red[t].y += red[t+64].y;
                   red[t].z += red[t+64].z; red[t].w += red[t+64].w; }
    __syncthreads();
    if (t < 32) {
      float4 o = red[t];
      o.x += red[t+32].x; o.y += red[t+32].y; o.z += red[t+32].z; o.w += red[t+32].w;
      *reinterpret_cast<float4*>(Wcs + co * DDIM + q * 128 + t * 4) = o;
    }
    return;
  }
  // XCD-aware decode: xcd owns panels p in [xcd*4, xcd*4+4), all 8 mb each
  const int xcd = bx & 7, slot = bx >> 3;
  const int p = xcd * 4 + (slot >> 3);
  const int mb = slot & 7;
  const int z = p >> 3, jb = p & 7;
  const int m0 = mb * 32, j0 = jb * 64;
  const float* W = (z == 0) ? w3w : (z == 1) ? w4w : (z == 2) ? w5w : w3u;
  const int lane = t & 63, wv = t >> 6;
  const int am = t & 31, ag = (t >> 5) * 8;     // A: row am, k's ag..ag+7
  const int bjl = t & 63, bko = (t >> 6) * 16;  // B: row bjl (lane-major), 16 k's
  float4 ra0, ra1, rb[4], rb2[4];
  float acc[8] = {0.f, 0.f, 0.f, 0.f, 0.f, 0.f, 0.f, 0.f};

#define G1_LOAD(k0)                                                    \
  {                                                                    \
    const float* as = H + (size_t)(m0 + am) * DDIM + (k0) + ag;        \
    ra0 = ld4(as); ra1 = ld4(as + 4);                                  \
    if (z < 3) {                                                       \
      const float* bp = W + (size_t)(j0 + bjl) * 1024 + (k0) + bko;    \
      rb[0] = ld4(bp);        rb[1] = ld4(bp + 4);                     \
      rb[2] = ld4(bp + 8);    rb[3] = ld4(bp + 12);                    \
      rb2[0] = ld4(bp + 512); rb2[1] = ld4(bp + 516);                  \
      rb2[2] = ld4(bp + 520); rb2[3] = ld4(bp + 524);                  \
    } else {                                                           \
      const float* bp = W + (size_t)(j0 + bjl) * DDIM + (k0) + bko;    \
      rb[0] = ld4(bp);     rb[1] = ld4(bp + 4);                        \
      rb[2] = ld4(bp + 8); rb[3] = ld4(bp + 12);                       \
    }                                                                  \
  }

  G1_LOAD(0);
  for (int c = 0; c < 8; ++c) {
    __syncthreads();
    {
      float* da = sA + ag * 32 + am;
      ST4S(da, 32, ra0);
      ST4S(da + 4 * 32, 32, ra1);
      float* db = sB + bko * 64 + bjl;
      if (z < 3) {
#pragma unroll
        for (int i = 0; i < 4; ++i) {
          const float4 f = make_float4(rb[i].x + rb2[i].x, rb[i].y + rb2[i].y,
                                       rb[i].z + rb2[i].z, rb[i].w + rb2[i].w);
          ST4S(db + i * 4 * 64, 64, f);
        }
      } else {
#pragma unroll
        for (int i = 0; i < 4; ++i) ST4S(db + i * 4 * 64, 64, rb[i]);
      }
    }
    __syncthreads();
    if (c < 7) G1_LOAD((c + 1) * 64);  // prefetch next chunk during compute
#pragma unroll 16
    for (int kk = 0; kk < 64; ++kk) {
      const float b = sB[kk * 64 + lane];                 // stride-1: free
      const float4 a0 = ld4(sA + kk * 32 + wv * 8);       // wave-uniform bcast
      const float4 a1 = ld4(sA + kk * 32 + wv * 8 + 4);
      acc[0] = fmaf(a0.x, b, acc[0]); acc[1] = fmaf(a0.y, b, acc[1]);
      acc[2] = fmaf(a0.z, b, acc[2]); acc[3] = fmaf(a0.w, b, acc[3]);
      acc[4] = fmaf(a1.x, b, acc[4]); acc[5] = fmaf(a1.y, b, acc[5]);
      acc[6] = fmaf(a1.z, b, acc[6]); acc[7] = fmaf(a1.w, b, acc[7]);
    }
  }
#undef G1_LOAD
  float* op = hw + (size_t)z * (NOBJ * DDIM);
  const float bias = (z == 3) ? b3u[j0 + lane] : 0.f;
#pragma unroll
  for (int i = 0; i < 8; ++i)
    op[(size_t)(m0 + wv * 8 + i) * DDIM + j0 + lane] = acc[i] + bias;
  if (z < 3) {  // deterministic column partials over this block's 32 rows
    float s = acc[0] + acc[1] + acc[2] + acc[3] + acc[4] + acc[5] + acc[6] + acc[7];
    __syncthreads();
    sA[wv * 64 + lane] = s;
    __syncthreads();
    if (t < 64)
      psum[z * 4096 + mb * 512 + j0 + t] =
          sA[t] + sA[64 + t] + sA[128 + t] + sA[192 + t];
  }
}

// ---------------------------------------------------------------------------
// k_G2: rv = sig(fac*(svh4-hw4)+b4w+hu3); acc = (rv.H)*w5u^T; full GRU update
// fused in epilogue. Tile 16m x 64j, 4 waves x 4m. grid 128, XCD swizzle:
// jb = xcd (w5u panel pinned to one L2), mb = slot.
// ---------------------------------------------------------------------------
__global__ void __launch_bounds__(256) k_G2(
    const float* __restrict__ Hc, const float* __restrict__ hw,
    const float* __restrict__ psum, const float* __restrict__ mat,
    const float* __restrict__ b3w, const float* __restrict__ b4w,
    const float* __restrict__ b5w, const float* __restrict__ w5u,
    const float* __restrict__ b5u, float* __restrict__ Hn) {
  __shared__ float sA[64 * 16];  // rv*H chunk, [k][m]
  __shared__ float sB[64 * 64];  // w5u chunk, [k][j]
  __shared__ float sv4[DDIM];
  __shared__ float sv35[128];
  const int t = threadIdx.x;
  const int jb = blockIdx.x & 7, mb = blockIdx.x >> 3;
  const int m0 = mb * 16, j0 = jb * 64;
  const int lane = t & 63, wv = t >> 6;
  const float fac = mat[0] * (float)CNUM;
  const float* hw3 = hw;
  const float* hw4 = hw + NOBJ * DDIM;
  const float* hw5 = hw + 2 * NOBJ * DDIM;
  const float* hu3 = hw + 3 * NOBJ * DDIM;
  {  // svh4 (all 512), svh3/svh5 (this j-panel) from the 8 psum partials
    float2 a = make_float2(0.f, 0.f);
#pragma unroll
    for (int mt = 0; mt < 8; ++mt) {
      const float2 v = *reinterpret_cast<const float2*>(psum + 4096 + mt * 512 + t * 2);
      a.x += v.x; a.y += v.y;
    }
    sv4[t * 2] = a.x; sv4[t * 2 + 1] = a.y;
    if (t < 64) {
      const int j = j0 + t;
      float u = 0.f, w = 0.f;
#pragma unroll
      for (int mt = 0; mt < 8; ++mt) {
        u += psum[mt * 512 + j];
        w += psum[2 * 4096 + mt * 512 + j];
      }
      sv35[t] = u; sv35[64 + t] = w;
    }
  }
  const int am2 = t & 15, kg = (t >> 4) * 4;    // A: row am2, 4 k's
  const int bjl = t & 63, bko = (t >> 6) * 16;  // B: lane-major
  float4 rh4, ru3, rhh, rb4v, rbv[4];
  float acc[4] = {0.f, 0.f, 0.f, 0.f};

#define G2_LOAD(k0)                                                  \
  {                                                                  \
    const int ia = (m0 + am2) * DDIM + (k0) + kg;                    \
    rh4 = ld4(hw4 + ia); ru3 = ld4(hu3 + ia); rhh = ld4(Hc + ia);    \
    rb4v = ld4(b4w + (k0) + kg);                                     \
    const float* bp = w5u + (size_t)(j0 + bjl) * DDIM + (k0) + bko;  \
    rbv[0] = ld4(bp);     rbv[1] = ld4(bp + 4);                      \
    rbv[2] = ld4(bp + 8); rbv[3] = ld4(bp + 12);                     \
  }

  G2_LOAD(0);
  for (int c = 0; c < 8; ++c) {
    const int k0 = c * 64;
    __syncthreads();
    {
      const float4 s4 = ld4(sv4 + k0 + kg);
      float* da = sA + kg * 16 + am2;
      da[0]      = sigf(fac * (s4.x - rh4.x) + rb4v.x + ru3.x) * rhh.x;
      da[16]     = sigf(fac * (s4.y - rh4.y) + rb4v.y + ru3.y) * rhh.y;
      da[2 * 16] = sigf(fac * (s4.z - rh4.z) + rb4v.z + ru3.z) * rhh.z;
      da[3 * 16] = sigf(fac * (s4.w - rh4.w) + rb4v.w + ru3.w) * rhh.w;
      float* db = sB + bko * 64 + bjl;
#pragma unroll
      for (int i = 0; i < 4; ++i) ST4S(db + i * 4 * 64, 64, rbv[i]);
    }
    __syncthreads();
    if (c < 7) G2_LOAD((c + 1) * 64);
#pragma unroll 16
    for (int kk = 0; kk < 64; ++kk) {
      const float b = sB[kk * 64 + lane];
      const float4 a = ld4(sA + kk * 16 + wv * 4);
      acc[0] = fmaf(a.x, b, acc[0]); acc[1] = fmaf(a.y, b, acc[1]);
      acc[2] = fmaf(a.z, b, acc[2]); acc[3] = fmaf(a.w, b, acc[3]);
    }
  }
#undef G2_LOAD
  const int j = j0 + lane;
  const float sv3 = sv35[lane], sv5 = sv35[64 + lane];
  const float bb3 = b3w[j], bb5 = b5w[j], bbu = b5u[j];
#pragma unroll
  for (int i = 0; i < 4; ++i) {
    const int m = m0 + wv * 4 + i;
    const int idx = m * DDIM + j;
    const float zv = sigf(fac * (sv3 - hw3[idx]) + bb3 + hu3[idx]);
    const float hv = tanhf_(fac * (sv5 - hw5[idx]) + bb5 + acc[i] + bbu);
    Hn[idx] = (1.f - zv) * Hc[idx] + zv * hv;
  }
}

// ---------------------------------------------------------------------------
// k_out: Po[s] = (s?X:H) * wo[:, s*512:(s+1)*512]^T  (split at the concat).
// Tile 16m x 64j, grid 256, XCD swizzle: 2 (s,jb) panels per XCD.
// ---------------------------------------------------------------------------
__global__ void __launch_bounds__(256) k_out(const float* __restrict__ H,
                                             const float* __restrict__ X,
                                             const float* __restrict__ wo,
                                             float* __restrict__ Po) {
  __shared__ float sA[64 * 16];
  __shared__ float sB[64 * 64];
  const int t = threadIdx.x;
  const int xcd = blockIdx.x & 7, slot = blockIdx.x >> 3;
  const int pnl = xcd * 2 + (slot >> 4);
  const int mb = slot & 15;
  const int s = pnl >> 3, jb = pnl & 7;
  const int m0 = mb * 16, j0 = jb * 64;
  const float* A = s ? X : H;
  const int lane = t & 63, wv = t >> 6;
  const int am = t & 15, kg = (t >> 4) * 4;
  const int bjl = t & 63, bko = (t >> 6) * 16;
  float4 ra, rbv[4];
  float acc[4] = {0.f, 0.f, 0.f, 0.f};

#define KO_LOAD(k0)                                                            \
  {                                                                            \
    ra = ld4(A + (size_t)(m0 + am) * DDIM + (k0) + kg);                        \
    const float* bp = wo + (size_t)(j0 + bjl) * 1024 + s * 512 + (k0) + bko;   \
    rbv[0] = ld4(bp);     rbv[1] = ld4(bp + 4);                                \
    rbv[2] = ld4(bp + 8); rbv[3] = ld4(bp + 12);                               \
  }

  KO_LOAD(0);
  for (int c = 0; c < 8; ++c) {
    __syncthreads();
    {
      float* da = sA + kg * 16 + am;
      ST4S(da, 16, ra);
      float* db = sB + bko * 64 + bjl;
#pragma unroll
      for (int i = 0; i < 4; ++i) ST4S(db + i * 4 * 64, 64, rbv[i]);
    }
    __syncthreads();
    if (c < 7) KO_LOAD((c + 1) * 64);
#pragma unroll 16
    for (int kk = 0; kk < 64; ++kk) {
      const float b = sB[kk * 64 + lane];
      const float4 a = ld4(sA + kk * 16 + wv * 4);
      acc[0] = fmaf(a.x, b, acc[0]); acc[1] = fmaf(a.y, b, acc[1]);
      acc[2] = fmaf(a.z, b, acc[2]); acc[3] = fmaf(a.w, b, acc[3]);
    }
  }
#undef KO_LOAD
#pragma unroll
  for (int i = 0; i < 4; ++i)
    Po[(size_t)s * (NOBJ * DDIM) + (size_t)(m0 + wv * 4 + i) * DDIM + j0 + lane] = acc[i];
}

// ---------------------------------------------------------------------------
// k_obj: out = relu(Po0+Po1+bo) * Wcs^T + bc. Tile 8m x 64j, grid (32,3).
// ---------------------------------------------------------------------------
__global__ void __launch_bounds__(256) k_obj(const float* __restrict__ Po,
                                             const float* __restrict__ bo,
                                             const float* __restrict__ Wcs,
                                             const float* __restrict__ bc,
                                             float* __restrict__ out) {
  __shared__ float sA[64 * 8];
  __shared__ float sB[64 * 64];
  const int t = threadIdx.x;
  const int m0 = blockIdx.x * 8, j0 = blockIdx.y * 64;
  const int lane = t & 63, wv = t >> 6;
  const int am8 = t & 7, kg2 = (t >> 3) * 2;
  const int bjl = t & 63, bko = (t >> 6) * 16;
  const int co = j0 + bjl;
  float ra0, ra1;
  float4 rbv[4];
  float acc[2] = {0.f, 0.f};

#define OB_LOAD(k0)                                                            \
  {                                                                            \
    const int ia = (m0 + am8) * DDIM + (k0) + kg2;                             \
    const float2 p0 = *reinterpret_cast<const float2*>(Po + ia);               \
    const float2 p1 = *reinterpret_cast<const float2*>(Po + NOBJ * DDIM + ia); \
    const float2 bb = *reinterpret_cast<const float2*>(bo + (k0) + kg2);       \
    ra0 = fmaxf(p0.x + p1.x + bb.x, 0.f);                                      \
    ra1 = fmaxf(p0.y + p1.y + bb.y, 0.f);                                      \
    if (co < CNUM) {                                                           \
      const float* bp = Wcs + (size_t)co * DDIM + (k0) + bko;                  \
      rbv[0] = ld4(bp);     rbv[1] = ld4(bp + 4);                              \
      rbv[2] = ld4(bp + 8); rbv[3] = ld4(bp + 12);                             \
    } else {                                                                   \
      rbv[0] = rbv[1] = rbv[2] = rbv[3] = make_float4(0.f, 0.f, 0.f, 0.f);     \
    }                                                                          \
  }

  OB_LOAD(0);
  for (int c = 0; c < 8; ++c) {
    __syncthreads();
    {
      sA[kg2 * 8 + am8] = ra0;
      sA[(kg2 + 1) * 8 + am8] = ra1;
      float* db = sB + bko * 64 + bjl;
#pragma unroll
      for (int i = 0; i < 4; ++i) ST4S(db + i * 4 * 64, 64, rbv[i]);
    }
    __syncthreads();
    if (c < 7) OB_LOAD((c + 1) * 64);
#pragma unroll 16
    for (int kk = 0; kk < 64; ++kk) {
      const float b = sB[kk * 64 + lane];
      const float2 a = *reinterpret_cast<const float2*>(sA + kk * 8 + wv * 2);
      acc[0] = fmaf(a.x, b, acc[0]);
      acc[1] = fmaf(a.y, b, acc[1]);
    }
  }
#undef OB_LOAD
  const int c_ = j0 + lane;
  if (c_ < CNUM) {
    const float bcv = bc[c_];
#pragma unroll
    for (int i = 0; i < 2; ++i)
      out[(m0 + wv * 2 + i) * CNUM + c_] = acc[i] + bcv;
  }
}

extern "C" void kernel_launch(void* const* d_in, const int* in_sizes, int n_in,
                              void* d_out, int out_size, void* d_ws, size_t ws_size,
                              hipStream_t stream) {
  const float* X = (const float*)d_in[0];
  const float* mat = (const float*)d_in[1];
  const float* w3w = (const float*)d_in[2];
  const float* b3w = (const float*)d_in[3];
  const float* w3u = (const float*)d_in[4];
  const float* b3u = (const float*)d_in[5];
  const float* w4w = (const float*)d_in[6];
  const float* b4w = (const float*)d_in[7];
  // d_in[8], d_in[9] (w4u, b4u) unused — reference reuses w3u/b3u (faithful bug)
  const float* w5w = (const float*)d_in[10];
  const float* b5w = (const float*)d_in[11];
  const float* w5u = (const float*)d_in[12];
  const float* b5u = (const float*)d_in[13];
  const float* wo = (const float*)d_in[14];
  const float* bo = (const float*)d_in[15];
  const float* wc = (const float*)d_in[16];
  const float* bc = (const float*)d_in[17];
  float* out = (float*)d_out;
  float* ws = (float*)d_ws;

  // workspace (floats): ~4.6 MB
  float* Wcs = ws;               // 151*512    = 77312
  float* hw = Wcs + 77312;       // 4*256*512  = 524288 (hw3,hw4,hw5,hu3)
  float* psum = hw + 524288;     // 3*8*512    = 12288
  float* H0 = psum + 12288;      // 131072
  float* H1 = H0 + 131072;       // 131072
  float* Po = H1 + 131072;       // 2*131072

  // iter 1 (Hc = X): G1 with Wcs tail blocks (memory-bound, co-scheduled)
  k_G1<<<NG1 + CNUM * 4, 256, 0, stream>>>(X, w3w, w4w, w5w, w3u, b3u, hw, psum, wc, Wcs);
  k_G2<<<128, 256, 0, stream>>>(X, hw, psum, mat, b3w, b4w, b5w, w5u, b5u, H0);
  // iter 2
  k_G1<<<NG1, 256, 0, stream>>>(H0, w3w, w4w, w5w, w3u, b3u, hw, psum, wc, Wcs);
  k_G2<<<128, 256, 0, stream>>>(H0, hw, psum, mat, b3w, b4w, b5w, w5u, b5u, H1);
  // iter 3
  k_G1<<<NG1, 256, 0, stream>>>(H1, w3w, w4w, w5w, w3u, b3u, hw, psum, wc, Wcs);
  k_G2<<<128, 256, 0, stream>>>(H1, hw, psum, mat, b3w, b4w, b5w, w5u, b5u, H0);
  // epilogue
  k_out<<<256, 256, 0, stream>>>(H0, X, wo, Po);
  k_obj<<<dim3(32, 3), 256, 0, stream>>>(Po, bo, Wcs, bc, out);
}

// Round 8
// 112.258 us; speedup vs baseline: 1.7458x; 1.6256x over previous
//
#include <hip/hip_runtime.h>
#include <cmath>

constexpr int NOBJ = 256, CNUM = 151, DDIM = 512;
constexpr int NG1 = 512;          // G1 GEMM blocks: 4z x 8jb x 2kh x 8mb
constexpr int NB_DD = NOBJ * DDIM;

__device__ __forceinline__ float sigf(float x) { return 1.0f / (1.0f + __expf(-x)); }
__device__ __forceinline__ float tanhf_(float x) {
  float e = __expf(-2.0f * fabsf(x));
  float y = (1.0f - e) / (1.0f + e);
  return copysignf(y, x);
}
__device__ __forceinline__ float4 ld4(const float* p) { return *reinterpret_cast<const float4*>(p); }

// ---------------------------------------------------------------------------
// k_G1 (split-K=2): hwP[kh][z] partials of H*Wsum_z^T (z<3 folded on load) and
// H*w3u^T (+b3u at kh=0). Tile 32m x 64j x 256k. 4 waves; lane=j; 8m/wave.
// XCD pin: xcd=bid&7 owns 8 (z,jb,kh) panels x 8 mb -> panels L2-resident.
// A in LDS [k][32m] XOR-swizzled (col = m ^ 8*((k>>3)&3)): stores 2-way free,
// reads = aligned wave-uniform b128 broadcast. B in LDS [k][66]: 2-way free.
// Epilogue: psumP[kh][z][mb][512] column partials (deterministic).
// Tail blocks (first launch): Wcs[co][d] = sum_c wc[co][c*512+d].
// ---------------------------------------------------------------------------
__global__ void __launch_bounds__(256) k_G1(
    const float* __restrict__ H, const float* __restrict__ w3w,
    const float* __restrict__ w4w, const float* __restrict__ w5w,
    const float* __restrict__ w3u, const float* __restrict__ b3u,
    float* __restrict__ hwP, float* __restrict__ psumP,
    const float* __restrict__ wc, float* __restrict__ Wcs) {
  __shared__ float sA[64 * 32];
  __shared__ float sB[64 * 66];
  const int t = threadIdx.x;
  const int bx = blockIdx.x;
  if (bx >= NG1) {  // ---- fused Wcs tail (first launch only) ----
    const int bw = bx - NG1;
    const int co = bw >> 2, q = bw & 3;
    const int d = q * 128 + (t & 31) * 4;
    const int g = t >> 5;
    const float* row = wc + (size_t)co * (CNUM * DDIM);
    float4 s = make_float4(0.f, 0.f, 0.f, 0.f);
    for (int c = g; c < CNUM; c += 8) {
      const float4 v = ld4(row + c * DDIM + d);
      s.x += v.x; s.y += v.y; s.z += v.z; s.w += v.w;
    }
    float4* red = reinterpret_cast<float4*>(sA);
    red[t] = s;
    __syncthreads();
    if (t < 128) { red[t].x += red[t+128].x; red[t].y += red[t+128].y;
                   red[t].z += red[t+128].z; red[t].w += red[t+128].w; }
    __syncthreads();
    if (t < 64)  { red[t].x += red[t+64].x; red[t].y += red[t+64].y;
                   red[t].z += red[t+64].z; red[t].w += red[t+64].w; }
    __syncthreads();
    if (t < 32) {
      float4 o = red[t];
      o.x += red[t+32].x; o.y += red[t+32].y; o.z += red[t+32].z; o.w += red[t+32].w;
      *reinterpret_cast<float4*>(Wcs + co * DDIM + q * 128 + t * 4) = o;
    }
    return;
  }
  const int xcd = bx & 7, slot = bx >> 3;
  const int pp = xcd * 8 + (slot >> 3);
  const int mb = slot & 7;
  const int z = pp >> 4, jb = (pp >> 1) & 7, kh = pp & 1;
  const int m0 = mb * 32, j0 = jb * 64, ks = kh * 256;
  const float* W = (z == 0) ? w3w : (z == 1) ? w4w : (z == 2) ? w5w : w3u;
  const int lane = t & 63, wv = t >> 6;
  const int am = t >> 3, ak = (t & 7) * 8;   // A: row am (0-31), k ak..ak+7
  const int jr = t >> 2, kf = (t & 3) * 4;   // B: row jr (0-63), 4 k-quads i*16
  float4 ra0, ra1, rb[4], rb2[4];
  float acc[8] = {0.f, 0.f, 0.f, 0.f, 0.f, 0.f, 0.f, 0.f};

#define G1_LOAD(c)                                                        \
  {                                                                       \
    const float* ap = H + (size_t)(m0 + am) * DDIM + ks + (c) * 64 + ak;  \
    ra0 = ld4(ap); ra1 = ld4(ap + 4);                                     \
    if (z < 3) {                                                          \
      const float* bp = W + (size_t)(j0 + jr) * 1024 + ks + (c) * 64 + kf;\
      rb[0] = ld4(bp);        rb[1] = ld4(bp + 16);                       \
      rb[2] = ld4(bp + 32);   rb[3] = ld4(bp + 48);                       \
      rb2[0] = ld4(bp + 512); rb2[1] = ld4(bp + 528);                     \
      rb2[2] = ld4(bp + 544); rb2[3] = ld4(bp + 560);                     \
    } else {                                                              \
      const float* bp = W + (size_t)(j0 + jr) * DDIM + ks + (c) * 64 + kf;\
      rb[0] = ld4(bp);      rb[1] = ld4(bp + 16);                         \
      rb[2] = ld4(bp + 32); rb[3] = ld4(bp + 48);                         \
    }                                                                     \
  }

  G1_LOAD(0);
  for (int c = 0; c < 4; ++c) {
    __syncthreads();
    {  // A store: col = am ^ 8*((k>>3)&3); (k>>3) = t&7 for all 8 elems
      float* da = sA + ak * 32 + (am ^ (((t & 7) & 3) << 3));
      da[0]   = ra0.x; da[32]  = ra0.y; da[64]  = ra0.z; da[96]  = ra0.w;
      da[128] = ra1.x; da[160] = ra1.y; da[192] = ra1.z; da[224] = ra1.w;
      float* db = sB + kf * 66 + jr;
      if (z < 3) {
#pragma unroll
        for (int i = 0; i < 4; ++i) {
          db[(i * 16 + 0) * 66] = rb[i].x + rb2[i].x;
          db[(i * 16 + 1) * 66] = rb[i].y + rb2[i].y;
          db[(i * 16 + 2) * 66] = rb[i].z + rb2[i].z;
          db[(i * 16 + 3) * 66] = rb[i].w + rb2[i].w;
        }
      } else {
#pragma unroll
        for (int i = 0; i < 4; ++i) {
          db[(i * 16 + 0) * 66] = rb[i].x;
          db[(i * 16 + 1) * 66] = rb[i].y;
          db[(i * 16 + 2) * 66] = rb[i].z;
          db[(i * 16 + 3) * 66] = rb[i].w;
        }
      }
    }
    __syncthreads();
    if (c < 3) G1_LOAD(c + 1);  // in flight during compute
    for (int k8 = 0; k8 < 8; ++k8) {
      const int abase = (k8 * 8) * 32 + ((wv ^ (k8 & 3)) << 3);
#pragma unroll
      for (int u = 0; u < 8; ++u) {
        const int kk = k8 * 8 + u;
        const float b = sB[kk * 66 + lane];
        const float4 a0 = ld4(sA + abase + u * 32);
        const float4 a1 = ld4(sA + abase + u * 32 + 4);
        acc[0] = fmaf(a0.x, b, acc[0]); acc[1] = fmaf(a0.y, b, acc[1]);
        acc[2] = fmaf(a0.z, b, acc[2]); acc[3] = fmaf(a0.w, b, acc[3]);
        acc[4] = fmaf(a1.x, b, acc[4]); acc[5] = fmaf(a1.y, b, acc[5]);
        acc[6] = fmaf(a1.z, b, acc[6]); acc[7] = fmaf(a1.w, b, acc[7]);
      }
    }
  }
#undef G1_LOAD
  float* op = hwP + (size_t)(kh * 4 + z) * NB_DD;
  const float bias = (z == 3 && kh == 0) ? b3u[j0 + lane] : 0.f;
#pragma unroll
  for (int i = 0; i < 8; ++i)
    op[(size_t)(m0 + wv * 8 + i) * DDIM + j0 + lane] = acc[i] + bias;
  if (z < 3) {  // deterministic column partials over this block's 32 rows
    float s = acc[0] + acc[1] + acc[2] + acc[3] + acc[4] + acc[5] + acc[6] + acc[7];
    __syncthreads();
    sA[wv * 64 + lane] = s;
    __syncthreads();
    if (t < 64)
      psumP[((kh * 3 + z) * 8 + mb) * 512 + j0 + t] =
          sA[t] + sA[64 + t] + sA[128 + t] + sA[192 + t];
  }
}

// ---------------------------------------------------------------------------
// k_G2 (split-K=4): P5[kq] partial of (rv.H)*w5u^T over k-quarter kq.
// rv = sig(fac*(svh4-hw4)+b4w+hu3), hw4/hu3 summed from the 2 G1 halves.
// Tile 16m x 64j x 128k; grid 512 = 8jb x 4kq x 16mb; XCD pin on (jb,kq).
// A in LDS [k][16m] XOR-swizzled (col = m ^ 4*((k>>2)&3)), b128 uniform reads.
// ---------------------------------------------------------------------------
__global__ void __launch_bounds__(256) k_G2(
    const float* __restrict__ Hc, const float* __restrict__ hwP,
    const float* __restrict__ psumP, const float* __restrict__ mat,
    const float* __restrict__ b4w, const float* __restrict__ w5u,
    float* __restrict__ P5) {
  __shared__ float sA[64 * 16];
  __shared__ float sB[64 * 66];
  __shared__ float sv4s[128];
  const int t = threadIdx.x;
  const int bx = blockIdx.x;
  const int xcd = bx & 7, slot = bx >> 3;
  const int pp = xcd * 4 + (slot >> 4);
  const int mb = slot & 15;
  const int jb = pp >> 2, kq = pp & 3;
  const int m0 = mb * 16, j0 = jb * 64, kb = kq * 128;
  const int lane = t & 63, wv = t >> 6;
  const float fac = mat[0] * (float)CNUM;
  const float* hw4a = hwP + (size_t)1 * NB_DD;
  const float* hw4b = hwP + (size_t)5 * NB_DD;
  const float* hu3a = hwP + (size_t)3 * NB_DD;
  const float* hu3b = hwP + (size_t)7 * NB_DD;

  if (t < 128) {  // svh4 for this k-quarter = sum of 16 psum partials
    const int k = kb + t;
    float s = 0.f;
#pragma unroll
    for (int mt = 0; mt < 8; ++mt)
      s += psumP[(0 * 3 + 1) * 4096 + mt * 512 + k] +
           psumP[(1 * 3 + 1) * 4096 + mt * 512 + k];
    sv4s[t] = s;
  }

  const int m = t >> 4, k4 = (t & 15) * 4;   // A: row m (0-15), 4 k's
  const int jr = t >> 2, kf = (t & 3) * 4;   // B: row jr, 4 k-quads
  float4 rva;
  float4 rbv[4];
  float acc[4] = {0.f, 0.f, 0.f, 0.f};

#define G2_LOADB(c)                                                           \
  {                                                                           \
    const float* bp = w5u + (size_t)(j0 + jr) * DDIM + kb + (c) * 64 + kf;    \
    rbv[0] = ld4(bp);      rbv[1] = ld4(bp + 16);                             \
    rbv[2] = ld4(bp + 32); rbv[3] = ld4(bp + 48);                             \
  }
#define G2_LOADA(c)                                                           \
  {                                                                           \
    const int kg = kb + (c) * 64 + k4;                                        \
    const int idx = (m0 + m) * DDIM + kg;                                     \
    const float4 h4x = ld4(hw4a + idx), h4y = ld4(hw4b + idx);                \
    const float4 u3x = ld4(hu3a + idx), u3y = ld4(hu3b + idx);                \
    const float4 hh = ld4(Hc + idx);                                          \
    const float4 b4 = ld4(b4w + kg);                                          \
    rva.x = h4x.x + h4y.x; rva.y = h4x.y + h4y.y;                             \
    rva.z = h4x.z + h4y.z; rva.w = h4x.w + h4y.w;                             \
    ru3.x = u3x.x + u3y.x; ru3.y = u3x.y + u3y.y;                             \
    ru3.z = u3x.z + u3y.z; ru3.w = u3x.w + u3y.w;                             \
    rhh = hh; rb4 = b4;                                                       \
  }
  float4 ru3, rhh, rb4;

  G2_LOADA(0); G2_LOADB(0);
  for (int c = 0; c < 2; ++c) {
    __syncthreads();
    {  // rv*H store, col = m ^ 4*((k>>2)&3); (k>>2)&3 = (t&15)&3 const
      const int kloc = c * 64 + k4;
      const float4 s4 = ld4(sv4s + kloc);
      float* da = sA + k4 * 16 + (m ^ (((t & 15) & 3) << 2));
      da[0]  = sigf(fac * (s4.x - rva.x) + rb4.x + ru3.x) * rhh.x;
      da[16] = sigf(fac * (s4.y - rva.y) + rb4.y + ru3.y) * rhh.y;
      da[32] = sigf(fac * (s4.z - rva.z) + rb4.z + ru3.z) * rhh.z;
      da[48] = sigf(fac * (s4.w - rva.w) + rb4.w + ru3.w) * rhh.w;
      float* db = sB + kf * 66 + jr;
#pragma unroll
      for (int i = 0; i < 4; ++i) {
        db[(i * 16 + 0) * 66] = rbv[i].x;
        db[(i * 16 + 1) * 66] = rbv[i].y;
        db[(i * 16 + 2) * 66] = rbv[i].z;
        db[(i * 16 + 3) * 66] = rbv[i].w;
      }
    }
    __syncthreads();
    if (c < 1) { G2_LOADA(1); G2_LOADB(1); }
    for (int k4o = 0; k4o < 16; ++k4o) {
      const int abase = (k4o * 4) * 16 + ((wv ^ (k4o & 3)) << 2);
#pragma unroll
      for (int u = 0; u < 4; ++u) {
        const int kk = k4o * 4 + u;
        const float b = sB[kk * 66 + lane];
        const float4 a = ld4(sA + abase + u * 16);
        acc[0] = fmaf(a.x, b, acc[0]); acc[1] = fmaf(a.y, b, acc[1]);
        acc[2] = fmaf(a.z, b, acc[2]); acc[3] = fmaf(a.w, b, acc[3]);
      }
    }
  }
#undef G2_LOADA
#undef G2_LOADB
#pragma unroll
  for (int i = 0; i < 4; ++i)
    P5[(size_t)kq * NB_DD + (size_t)(m0 + wv * 4 + i) * DDIM + j0 + lane] = acc[i];
}

// ---------------------------------------------------------------------------
// k_upd: Hn = (1-zv)*H + zv*tanh(fac*(sv5-hw5)+b5w+SumP5+b5u), zv likewise.
// grid 512 = 32 mb(8 rows) x 16 jb(32 cols); sv3/sv5 from psum in LDS.
// ---------------------------------------------------------------------------
__global__ void __launch_bounds__(256) k_upd(
    const float* __restrict__ Hc, const float* __restrict__ hwP,
    const float* __restrict__ psumP, const float* __restrict__ P5,
    const float* __restrict__ mat, const float* __restrict__ b3w,
    const float* __restrict__ b5w, const float* __restrict__ b5u,
    float* __restrict__ Hn) {
  __shared__ float s3[32], s5[32];
  const int t = threadIdx.x;
  const int m0 = (blockIdx.x >> 4) * 8;
  const int j0 = (blockIdx.x & 15) * 32;
  const float fac = mat[0] * (float)CNUM;
  if (t < 32) {
    const int j = j0 + t;
    float a = 0.f, b = 0.f;
#pragma unroll
    for (int mt = 0; mt < 8; ++mt) {
      a += psumP[mt * 512 + j] + psumP[3 * 4096 + mt * 512 + j];
      b += psumP[2 * 4096 + mt * 512 + j] + psumP[5 * 4096 + mt * 512 + j];
    }
    s3[t] = a; s5[t] = b;
  }
  __syncthreads();
  const int r = t >> 5, c = t & 31;
  const int m = m0 + r, j = j0 + c;
  const int idx = m * DDIM + j;
  const float hw3 = hwP[idx] + hwP[(size_t)4 * NB_DD + idx];
  const float hw5 = hwP[(size_t)2 * NB_DD + idx] + hwP[(size_t)6 * NB_DD + idx];
  const float hu3 = hwP[(size_t)3 * NB_DD + idx] + hwP[(size_t)7 * NB_DD + idx];
  const float p5 = P5[idx] + P5[(size_t)NB_DD + idx] +
                   P5[(size_t)2 * NB_DD + idx] + P5[(size_t)3 * NB_DD + idx];
  const float zv = sigf(fac * (s3[c] - hw3) + b3w[j] + hu3);
  const float hv = tanhf_(fac * (s5[c] - hw5) + b5w[j] + p5 + b5u[j]);
  Hn[idx] = (1.f - zv) * Hc[idx] + zv * hv;
}

// ---------------------------------------------------------------------------
// k_out (split-K=4 at the [H|X] concat + halves): Po[p] partials of
// [H|X]*wo^T. Tile 16m x 64j x 256k; grid 512 = 8jb x 4p x 16mb; XCD pinned.
// ---------------------------------------------------------------------------
__global__ void __launch_bounds__(256) k_out(const float* __restrict__ H,
                                             const float* __restrict__ X,
                                             const float* __restrict__ wo,
                                             float* __restrict__ Po) {
  __shared__ float sA[64 * 16];
  __shared__ float sB[64 * 66];
  const int t = threadIdx.x;
  const int bx = blockIdx.x;
  const int xcd = bx & 7, slot = bx >> 3;
  const int pp = xcd * 4 + (slot >> 4);
  const int mb = slot & 15;
  const int jb = pp >> 2, p = pp & 3;
  const int s = p >> 1, ksh = p & 1;
  const int m0 = mb * 16, j0 = jb * 64, kb = ksh * 256;
  const float* A = s ? X : H;
  const int lane = t & 63, wv = t >> 6;
  const int m = t >> 4, k4 = (t & 15) * 4;
  const int jr = t >> 2, kf = (t & 3) * 4;
  float4 rav, rbv[4];
  float acc[4] = {0.f, 0.f, 0.f, 0.f};

#define KO_LOAD(c)                                                              \
  {                                                                             \
    rav = ld4(A + (size_t)(m0 + m) * DDIM + kb + (c) * 64 + k4);                \
    const float* bp = wo + (size_t)(j0 + jr) * 1024 + s * 512 + kb + (c) * 64 + kf; \
    rbv[0] = ld4(bp);      rbv[1] = ld4(bp + 16);                               \
    rbv[2] = ld4(bp + 32); rbv[3] = ld4(bp + 48);                               \
  }

  KO_LOAD(0);
  for (int c = 0; c < 4; ++c) {
    __syncthreads();
    {
      float* da = sA + k4 * 16 + (m ^ (((t & 15) & 3) << 2));
      da[0] = rav.x; da[16] = rav.y; da[32] = rav.z; da[48] = rav.w;
      float* db = sB + kf * 66 + jr;
#pragma unroll
      for (int i = 0; i < 4; ++i) {
        db[(i * 16 + 0) * 66] = rbv[i].x;
        db[(i * 16 + 1) * 66] = rbv[i].y;
        db[(i * 16 + 2) * 66] = rbv[i].z;
        db[(i * 16 + 3) * 66] = rbv[i].w;
      }
    }
    __syncthreads();
    if (c < 3) KO_LOAD(c + 1);
    for (int k4o = 0; k4o < 16; ++k4o) {
      const int abase = (k4o * 4) * 16 + ((wv ^ (k4o & 3)) << 2);
#pragma unroll
      for (int u = 0; u < 4; ++u) {
        const int kk = k4o * 4 + u;
        const float b = sB[kk * 66 + lane];
        const float4 a = ld4(sA + abase + u * 16);
        acc[0] = fmaf(a.x, b, acc[0]); acc[1] = fmaf(a.y, b, acc[1]);
        acc[2] = fmaf(a.z, b, acc[2]); acc[3] = fmaf(a.w, b, acc[3]);
      }
    }
  }
#undef KO_LOAD
#pragma unroll
  for (int i = 0; i < 4; ++i)
    Po[(size_t)p * NB_DD + (size_t)(m0 + wv * 4 + i) * DDIM + j0 + lane] = acc[i];
}

// ---------------------------------------------------------------------------
// k_obj: out = relu(sum Po + bo) * Wcs^T + bc. Tile 8m x 64j, grid (32,3).
// A (relu'd activations, 8x512) staged once; B per 64-chunk.
// ---------------------------------------------------------------------------
__global__ void __launch_bounds__(256) k_obj(const float* __restrict__ Po,
                                             const float* __restrict__ bo,
                                             const float* __restrict__ Wcs,
                                             const float* __restrict__ bc,
                                             float* __restrict__ out) {
  __shared__ float sAo[8 * 519];
  __shared__ float sB[64 * 66];
  const int t = threadIdx.x;
  const int m0 = blockIdx.x * 8, j0 = blockIdx.y * 64;
  const int lane = t & 63, wv = t >> 6;
  const int jr = t >> 2, kf = (t & 3) * 4;
  const int co = j0 + jr;
  {  // stage relu(sum Po + bo) for 8 rows x 512 k
    const int m = t >> 5, ks4 = (t & 31) * 4;
#pragma unroll
    for (int kb2 = 0; kb2 < 4; ++kb2) {
      const int k = kb2 * 128 + ks4;
      const int idx = (m0 + m) * DDIM + k;
      const float4 p0 = ld4(Po + idx);
      const float4 p1 = ld4(Po + (size_t)NB_DD + idx);
      const float4 p2 = ld4(Po + (size_t)2 * NB_DD + idx);
      const float4 p3 = ld4(Po + (size_t)3 * NB_DD + idx);
      const float4 bb = ld4(bo + k);
      float* da = sAo + m * 519 + k;
      da[0] = fmaxf(p0.x + p1.x + p2.x + p3.x + bb.x, 0.f);
      da[1] = fmaxf(p0.y + p1.y + p2.y + p3.y + bb.y, 0.f);
      da[2] = fmaxf(p0.z + p1.z + p2.z + p3.z + bb.z, 0.f);
      da[3] = fmaxf(p0.w + p1.w + p2.w + p3.w + bb.w, 0.f);
    }
  }
  float4 rbv[4];
  float acc[2] = {0.f, 0.f};
#define OB_LOADB(c)                                                         \
  {                                                                         \
    if (co < CNUM) {                                                        \
      const float* bp = Wcs + (size_t)co * DDIM + (c) * 64 + kf;            \
      rbv[0] = ld4(bp);      rbv[1] = ld4(bp + 16);                         \
      rbv[2] = ld4(bp + 32); rbv[3] = ld4(bp + 48);                         \
    } else {                                                                \
      rbv[0] = rbv[1] = rbv[2] = rbv[3] = make_float4(0.f, 0.f, 0.f, 0.f);  \
    }                                                                       \
  }
  OB_LOADB(0);
  for (int c = 0; c < 8; ++c) {
    __syncthreads();
    {
      float* db = sB + kf * 66 + jr;
#pragma unroll
      for (int i = 0; i < 4; ++i) {
        db[(i * 16 + 0) * 66] = rbv[i].x;
        db[(i * 16 + 1) * 66] = rbv[i].y;
        db[(i * 16 + 2) * 66] = rbv[i].z;
        db[(i * 16 + 3) * 66] = rbv[i].w;
      }
    }
    __syncthreads();
    if (c < 7) OB_LOADB(c + 1);
    const float* a0p = sAo + (wv * 2) * 519 + c * 64;
    const float* a1p = a0p + 519;
#pragma unroll 16
    for (int kk = 0; kk < 64; ++kk) {
      const float b = sB[kk * 66 + lane];
      acc[0] = fmaf(a0p[kk], b, acc[0]);
      acc[1] = fmaf(a1p[kk], b, acc[1]);
    }
  }
#undef OB_LOADB
  const int c_ = j0 + lane;
  if (c_ < CNUM) {
    const float bcv = bc[c_];
    out[(m0 + wv * 2 + 0) * CNUM + c_] = acc[0] + bcv;
    out[(m0 + wv * 2 + 1) * CNUM + c_] = acc[1] + bcv;
  }
}

extern "C" void kernel_launch(void* const* d_in, const int* in_sizes, int n_in,
                              void* d_out, int out_size, void* d_ws, size_t ws_size,
                              hipStream_t stream) {
  const float* X = (const float*)d_in[0];
  const float* mat = (const float*)d_in[1];
  const float* w3w = (const float*)d_in[2];
  const float* b3w = (const float*)d_in[3];
  const float* w3u = (const float*)d_in[4];
  const float* b3u = (const float*)d_in[5];
  const float* w4w = (const float*)d_in[6];
  const float* b4w = (const float*)d_in[7];
  // d_in[8], d_in[9] (w4u, b4u) unused — reference reuses w3u/b3u (faithful bug)
  const float* w5w = (const float*)d_in[10];
  const float* b5w = (const float*)d_in[11];
  const float* w5u = (const float*)d_in[12];
  const float* b5u = (const float*)d_in[13];
  const float* wo = (const float*)d_in[14];
  const float* bo = (const float*)d_in[15];
  const float* wc = (const float*)d_in[16];
  const float* bc = (const float*)d_in[17];
  float* out = (float*)d_out;
  float* ws = (float*)d_ws;

  // workspace (floats): ~9.8 MB
  float* Wcs = ws;                    // 151*512          = 77312
  float* hwP = Wcs + 77312;           // 2kh*4z*256*512   = 1048576
  float* psumP = hwP + 1048576;       // 2kh*3z*8mb*512   = 24576
  float* P5 = psumP + 24576;          // 4kq*256*512      = 524288
  float* Po = P5 + 524288;            // 4p*256*512       = 524288
  float* H0 = Po + 524288;            // 131072
  float* H1 = H0 + 131072;            // 131072

  // iter 1 (Hc = X): G1 with Wcs tail blocks (memory-bound, co-scheduled)
  k_G1<<<NG1 + CNUM * 4, 256, 0, stream>>>(X, w3w, w4w, w5w, w3u, b3u, hwP, psumP, wc, Wcs);
  k_G2<<<512, 256, 0, stream>>>(X, hwP, psumP, mat, b4w, w5u, P5);
  k_upd<<<512, 256, 0, stream>>>(X, hwP, psumP, P5, mat, b3w, b5w, b5u, H0);
  // iter 2
  k_G1<<<NG1, 256, 0, stream>>>(H0, w3w, w4w, w5w, w3u, b3u, hwP, psumP, wc, Wcs);
  k_G2<<<512, 256, 0, stream>>>(H0, hwP, psumP, mat, b4w, w5u, P5);
  k_upd<<<512, 256, 0, stream>>>(H0, hwP, psumP, P5, mat, b3w, b5w, b5u, H1);
  // iter 3
  k_G1<<<NG1, 256, 0, stream>>>(H1, w3w, w4w, w5w, w3u, b3u, hwP, psumP, wc, Wcs);
  k_G2<<<512, 256, 0, stream>>>(H1, hwP, psumP, mat, b4w, w5u, P5);
  k_upd<<<512, 256, 0, stream>>>(H1, hwP, psumP, P5, mat, b3w, b5w, b5u, H0);
  // epilogue
  k_out<<<512, 256, 0, stream>>>(H0, X, wo, Po);
  k_obj<<<dim3(32, 3), 256, 0, stream>>>(Po, bo, Wcs, bc, out);
}